// Round 9
// baseline (745.820 us; speedup 1.0000x reference)
//
#include <hip/hip_runtime.h>
#include <hip/hip_bf16.h>

#define BB 4096
#define DD 64
#define HH 512

typedef __hip_bfloat16 bf16;
typedef __attribute__((ext_vector_type(8))) short bf16x8;
typedef __attribute__((ext_vector_type(4))) float f32x4;

__device__ __forceinline__ float bf2f(bf16 x) { return __bfloat162float(x); }
__device__ __forceinline__ float u16tof(unsigned short u) {
  union { unsigned int i; float f; } v; v.i = ((unsigned int)u) << 16; return v.f;
}

// ws: Xbf | Ybf (B*H bf16 each) | W2bf | V2bf (H*H bf16) | W1T | W3T (bf16)
// Q_diag stashed f32 in out[:, 64:] by k3(act=1), consumed+overwritten by k4.

// ---------------------------------------------------------------------------
// cvt: grid 576. [0,256) W2bf; [256,512) V2bf; [512,544) W1T; [544,576) W3T.
// W1T[d*512+k] = W1[k*64+d];  W3T[h*64+d] = W3[d*512+h].
// ---------------------------------------------------------------------------
__global__ __launch_bounds__(256) void cvt_weights(
    const float* __restrict__ W2, const float* __restrict__ V2,
    const float* __restrict__ W1, const float* __restrict__ W3,
    bf16* __restrict__ W2bf, bf16* __restrict__ V2bf,
    bf16* __restrict__ W1T, bf16* __restrict__ W3T) {
  int blk = blockIdx.x, t = threadIdx.x;
  if (blk < 512) {
    const float* src = (blk < 256) ? W2 : V2;
    bf16* dst = (blk < 256) ? W2bf : V2bf;
    int i = ((blk & 255) * 256 + t) * 4;
    float4 v = *(const float4*)(src + i);
    bf16 o[4] = {__float2bfloat16(v.x), __float2bfloat16(v.y),
                 __float2bfloat16(v.z), __float2bfloat16(v.w)};
    *(uint2*)(dst + i) = *(uint2*)o;
  } else if (blk < 544) {
    int e = (blk - 512) * 1024 + t * 4;          // W1T elem index
    int d = e >> 9, k0 = e & 511;
    bf16 o[4];
#pragma unroll
    for (int j = 0; j < 4; ++j) o[j] = __float2bfloat16(W1[(size_t)(k0 + j) * 64 + d]);
    *(uint2*)(W1T + e) = *(uint2*)o;
  } else {
    int e = (blk - 544) * 1024 + t * 4;          // W3T elem index
    int h = e >> 6, d0 = e & 63;
    bf16 o[4];
#pragma unroll
    for (int j = 0; j < 4; ++j) o[j] = __float2bfloat16(W3[(size_t)(d0 + j) * 512 + h]);
    *(uint2*)(W3T + e) = *(uint2*)o;
  }
}

// ---------------------------------------------------------------------------
// k1: Xbf[b,h] = bf16(tanh(mu @ W^T + bias)), K=64. (fp32 VALU; cheap)
// ---------------------------------------------------------------------------
__global__ __launch_bounds__(256) void k1_stage1(
    const float* __restrict__ states,
    const float* __restrict__ W, const float* __restrict__ bias,
    bf16* __restrict__ out) {
  __shared__ __align__(16) float aT[64 * 68];
  __shared__ __align__(16) float wT[64 * 68];
  const int bt = blockIdx.x * 64;
  const int ht = blockIdx.y * 64;
  const int t = threadIdx.x;

#pragma unroll
  for (int i = 0; i < 16; ++i) {
    int idx = t + i * 256;
    int r = idx >> 6, k = idx & 63;
    aT[k * 68 + r] = states[(size_t)(bt + r) * 128 + k];
    wT[k * 68 + r] = W[(size_t)(ht + r) * 64 + k];
  }
  __syncthreads();

  const int bi = (t & 15) * 4, hj = (t >> 4) * 4;
  float acc[4][4] = {};
#pragma unroll
  for (int k = 0; k < 64; ++k) {
    float4 av = *(const float4*)(aT + k * 68 + bi);
    float4 bv = *(const float4*)(wT + k * 68 + hj);
    float ar[4] = {av.x, av.y, av.z, av.w};
    float br[4] = {bv.x, bv.y, bv.z, bv.w};
#pragma unroll
    for (int i = 0; i < 4; ++i)
#pragma unroll
      for (int j = 0; j < 4; ++j) acc[i][j] += ar[i] * br[j];
  }
#pragma unroll
  for (int j = 0; j < 4; ++j) {
    float bsv = bias[ht + hj + j];
#pragma unroll
    for (int i = 0; i < 4; ++i)
      out[(size_t)(bt + bi + i) * HH + ht + hj + j] =
          __float2bfloat16(tanhf(acc[i][j] + bsv));
  }
}

// ---------------------------------------------------------------------------
// k2 (MFMA): Ybf = bf16(tanh(Xbf @ Wbf^T + bias)). grid (B/64, 4): 64b x 128h.
// A-tile resident LDS (64x520 bf16); B-frags direct global (Wbf L2-resident).
// Barriers: 1 (after A copy). 2 blocks/CU.
// ---------------------------------------------------------------------------
__global__ __launch_bounds__(256) void k2_mfma(
    const bf16* __restrict__ A, const bf16* __restrict__ Wbf,
    const float* __restrict__ bias, bf16* __restrict__ out) {
  __shared__ __align__(16) bf16 At[64 * 520];
  const int bt = blockIdx.x * 64;
  const int t = threadIdx.x;
  const int lane = t & 63;
  const int w = t >> 6;
  const int c = lane & 15;
  const int q = lane >> 4;

#pragma unroll
  for (int i = 0; i < 16; ++i) {
    int u = t + i * 256;
    int row = u >> 6, kb = (u & 63) * 8;
    *(uint4*)(At + row * 520 + kb) = *(const uint4*)(A + (size_t)(bt + row) * HH + kb);
  }
  __syncthreads();

  const int colbase = blockIdx.y * 128 + w * 32;
  f32x4 acc[4][2] = {};
#pragma unroll
  for (int kc = 0; kc < 16; ++kc) {
    bf16x8 bfrag[2];
#pragma unroll
    for (int nt = 0; nt < 2; ++nt)
      bfrag[nt] = __builtin_bit_cast(bf16x8,
          *(const uint4*)(Wbf + (size_t)(colbase + nt * 16 + c) * HH + kc * 32 + q * 8));
#pragma unroll
    for (int mt = 0; mt < 4; ++mt) {
      bf16x8 afrag = __builtin_bit_cast(bf16x8,
          *(const uint4*)(At + (mt * 16 + c) * 520 + kc * 32 + q * 8));
#pragma unroll
      for (int nt = 0; nt < 2; ++nt)
        acc[mt][nt] = __builtin_amdgcn_mfma_f32_16x16x32_bf16(
            afrag, bfrag[nt], acc[mt][nt], 0, 0, 0);
    }
  }
#pragma unroll
  for (int nt = 0; nt < 2; ++nt) {
    int col = colbase + nt * 16 + c;
    float bs = bias[col];
#pragma unroll
    for (int mt = 0; mt < 4; ++mt)
#pragma unroll
      for (int r = 0; r < 4; ++r) {
        int b = bt + mt * 16 + q * 4 + r;
        out[(size_t)b * HH + col] = __float2bfloat16(tanhf(acc[mt][nt][r] + bs));
      }
  }
}

// ---------------------------------------------------------------------------
// k3: tmp = A @ W^T + bias (A bf16, W f32 64 x 512). act? softplus. out f32.
// ---------------------------------------------------------------------------
__global__ __launch_bounds__(256) void k3_stage3(
    const bf16* __restrict__ A,
    const float* __restrict__ W, const float* __restrict__ bias,
    float* __restrict__ out, int colOff, int act) {
  __shared__ __align__(16) float aT[32 * 68];
  __shared__ __align__(16) float wT[32 * 68];
  const int bt = blockIdx.x * 64;
  const int t = threadIdx.x;
  const int bi = (t & 15) * 4, oj = (t >> 4) * 4;
  float acc[4][4] = {};

  for (int kc = 0; kc < HH; kc += 32) {
#pragma unroll
    for (int i = 0; i < 8; ++i) {
      int idx = t + i * 256;
      int r = idx >> 5, k = idx & 31;
      aT[k * 68 + r] = bf2f(A[(size_t)(bt + r) * HH + kc + k]);
      wT[k * 68 + r] = W[(size_t)r * HH + kc + k];
    }
    __syncthreads();
#pragma unroll
    for (int k = 0; k < 32; ++k) {
      float4 av = *(const float4*)(aT + k * 68 + bi);
      float4 bv = *(const float4*)(wT + k * 68 + oj);
      float ar[4] = {av.x, av.y, av.z, av.w};
      float br[4] = {bv.x, bv.y, bv.z, bv.w};
#pragma unroll
      for (int i = 0; i < 4; ++i)
#pragma unroll
        for (int j = 0; j < 4; ++j) acc[i][j] += ar[i] * br[j];
    }
    __syncthreads();
  }
#pragma unroll
  for (int j = 0; j < 4; ++j) {
    float bsv = bias[oj + j];
#pragma unroll
    for (int i = 0; i < 4; ++i) {
      float v = acc[i][j] + bsv;
      if (act) v = fmaxf(v, 0.0f) + log1pf(expf(-fabsf(v)));
      out[(size_t)(bt + bi + i) * 128 + colOff + oj + j] = v;
    }
  }
}

// ---------------------------------------------------------------------------
// k4 (MFMA v3): one block per b (4096 blocks), all 64 d.
// Bres[d][k] = d1[b,k]*W1T[d,k] resident (64x520 bf16). Wave w owns h-rows
// [w*128, w*128+128); A-frags = W2bf rows DIRECT FROM GLOBAL (no barrier).
// C[h,d] per h-tile -> epilogue folds (1-h2^2)*W3T[h,d]. 2 barriers total.
// LDS ~72 KB -> 2 blocks/CU.
// ---------------------------------------------------------------------------
__global__ __launch_bounds__(256) void k4_mfma(
    const bf16* __restrict__ Xbf, const bf16* __restrict__ Ybf,
    const bf16* __restrict__ W1T, const bf16* __restrict__ W2bf,
    const bf16* __restrict__ W3T, const float* __restrict__ states,
    float* __restrict__ out) {
  __shared__ __align__(16) bf16 Bres[64 * 520];   // 66560 B
  __shared__ __align__(16) float d1s[512];
  __shared__ __align__(16) float d2s[512];
  __shared__ float red[4 * 64];

  const int b = blockIdx.x;
  const int t = threadIdx.x;
  const int lane = t & 63;
  const int w = t >> 6;
  const int c = lane & 15;
  const int q = lane >> 4;

#pragma unroll
  for (int i = 0; i < 2; ++i) {
    int k = t + i * 256;
    float x = bf2f(Xbf[(size_t)b * HH + k]);
    d1s[k] = 1.0f - x * x;
    float y = bf2f(Ybf[(size_t)b * HH + k]);
    d2s[k] = 1.0f - y * y;
  }
  __syncthreads();

  // build Bres
#pragma unroll
  for (int i = 0; i < 16; ++i) {
    int u = t + i * 256;
    int d = u >> 6, kb = (u & 63) * 8;
    uint4 wr = *(const uint4*)(W1T + (size_t)d * HH + kb);
    const unsigned short* ws = (const unsigned short*)&wr;
    bf16 o[8];
#pragma unroll
    for (int j = 0; j < 8; ++j)
      o[j] = __float2bfloat16(d1s[kb + j] * u16tof(ws[j]));
    *(uint4*)(Bres + d * 520 + kb) = *(const uint4*)o;
  }
  __syncthreads();

  float jp[4] = {0.f, 0.f, 0.f, 0.f};
  for (int ht = 0; ht < 8; ++ht) {
    const int h0 = w * 128 + ht * 16;
    f32x4 acc[4] = {f32x4{0,0,0,0}, f32x4{0,0,0,0}, f32x4{0,0,0,0}, f32x4{0,0,0,0}};
#pragma unroll
    for (int kc = 0; kc < 16; ++kc) {
      bf16x8 afrag = __builtin_bit_cast(bf16x8,
          *(const uint4*)(W2bf + (size_t)(h0 + c) * HH + kc * 32 + q * 8));
#pragma unroll
      for (int nt = 0; nt < 4; ++nt) {
        bf16x8 bfrag = __builtin_bit_cast(bf16x8,
            *(const uint4*)(Bres + (nt * 16 + c) * 520 + kc * 32 + q * 8));
        acc[nt] = __builtin_amdgcn_mfma_f32_16x16x32_bf16(afrag, bfrag, acc[nt], 0, 0, 0);
      }
    }
    // epilogue: fold (1-h2^2) * W3T[h, d]
#pragma unroll
    for (int r = 0; r < 4; ++r) {
      int h = h0 + q * 4 + r;
      float e2 = d2s[h];
#pragma unroll
      for (int nt = 0; nt < 4; ++nt) {
        float w3 = bf2f(W3T[(size_t)h * 64 + nt * 16 + c]);
        jp[nt] += acc[nt][r] * e2 * w3;
      }
    }
  }

  // sum over q (rows) within wave, then across waves
#pragma unroll
  for (int nt = 0; nt < 4; ++nt) {
    float v = jp[nt];
    v += __shfl_xor(v, 16);
    v += __shfl_xor(v, 32);
    jp[nt] = v;
  }
  if (q == 0) {
#pragma unroll
    for (int nt = 0; nt < 4; ++nt) red[w * 64 + nt * 16 + c] = jp[nt];
  }
  __syncthreads();
  if (t < 64) {
    float J = red[t] + red[64 + t] + red[128 + t] + red[192 + t];
    float sig = states[(size_t)b * 128 + 64 + t];
    float qd = out[(size_t)b * 128 + 64 + t];
    out[(size_t)b * 128 + 64 + t] = 2.0f * J * sig + qd;
  }
}

extern "C" void kernel_launch(void* const* d_in, const int* in_sizes, int n_in,
                              void* d_out, int out_size, void* d_ws, size_t ws_size,
                              hipStream_t stream) {
  // inputs: 0:t 1:states 2:W1 3:b1 4:W2 5:b2 6:W3 7:b3 8:V1 9:c1 10:V2 11:c2 12:V3 13:c3
  const float* states = (const float*)d_in[1];
  const float* W1 = (const float*)d_in[2];
  const float* b1 = (const float*)d_in[3];
  const float* W2 = (const float*)d_in[4];
  const float* b2 = (const float*)d_in[5];
  const float* W3 = (const float*)d_in[6];
  const float* b3 = (const float*)d_in[7];
  const float* V1 = (const float*)d_in[8];
  const float* c1 = (const float*)d_in[9];
  const float* V2 = (const float*)d_in[10];
  const float* c2 = (const float*)d_in[11];
  const float* V3 = (const float*)d_in[12];
  const float* c3 = (const float*)d_in[13];
  float* out = (float*)d_out;

  bf16* Xbf = (bf16*)d_ws;                         // B*H (4 MB)
  bf16* Ybf = Xbf + (size_t)BB * HH;               // B*H (4 MB)
  bf16* W2bf = Ybf + (size_t)BB * HH;              // H*H (0.5 MB)
  bf16* V2bf = W2bf + (size_t)HH * HH;             // H*H (0.5 MB)
  bf16* W1T = V2bf + (size_t)HH * HH;              // 512*64 (64 KB)
  bf16* W3T = W1T + (size_t)HH * DD;               // 512*64 (64 KB)

  cvt_weights<<<dim3(576), 256, 0, stream>>>(W2, V2, W1, W3, W2bf, V2bf, W1T, W3T);
  // Q path; stash Q_diag (softplus, f32) into out[:, 64:]
  k1_stage1<<<dim3(64, 8), 256, 0, stream>>>(states, V1, c1, Xbf);       // g1
  k2_mfma<<<dim3(64, 4), 256, 0, stream>>>(Xbf, V2bf, c2, Ybf);          // g2
  k3_stage3<<<dim3(64), 256, 0, stream>>>(Ybf, V3, c3, out, 64, 1);      // Qd
  // h path
  k1_stage1<<<dim3(64, 8), 256, 0, stream>>>(states, W1, b1, Xbf);       // h1
  k2_mfma<<<dim3(64, 4), 256, 0, stream>>>(Xbf, W2bf, b2, Ybf);          // h2
  k3_stage3<<<dim3(64), 256, 0, stream>>>(Ybf, W3, b3, out, 0, 0);       // mu
  // J_diag + final sigma_drift
  k4_mfma<<<dim3(BB), 256, 0, stream>>>(Xbf, Ybf, W1T, W2bf, W3T, states, out);
}

// Round 10
// 689.387 us; speedup vs baseline: 1.0819x; 1.0819x over previous
//
#include <hip/hip_runtime.h>
#include <hip/hip_bf16.h>

#define BB 4096
#define DD 64
#define HH 512

typedef __hip_bfloat16 bf16;
typedef __attribute__((ext_vector_type(8))) short bf16x8;
typedef __attribute__((ext_vector_type(4))) float f32x4;

__device__ __forceinline__ float bf2f(bf16 x) { return __bfloat162float(x); }
__device__ __forceinline__ float u16tof(unsigned short u) {
  union { unsigned int i; float f; } v; v.i = ((unsigned int)u) << 16; return v.f;
}

// ws layout (bf16 unless noted):
//   Xbf (B*H) | Ybf (B*H) | D1bf (B*H) | W2bf (H*H) | V2bf (H*H) |
//   W1T (64x512) | Jacc (B*64 f32)   total ~14.1 MB  (ws >= 16 MB proven R5)
// Q_diag stashed f32 in out[:,64:] by k3(act=1); combine() adds 2*J*sig.

// ---------------------------------------------------------------------------
// cvt: [0,256) W2bf; [256,512) V2bf; [512,544) W1T[d*512+k] = W1[k*64+d].
// ---------------------------------------------------------------------------
__global__ __launch_bounds__(256) void cvt_weights(
    const float* __restrict__ W2, const float* __restrict__ V2,
    const float* __restrict__ W1,
    bf16* __restrict__ W2bf, bf16* __restrict__ V2bf, bf16* __restrict__ W1T) {
  int blk = blockIdx.x, t = threadIdx.x;
  if (blk < 512) {
    const float* src = (blk < 256) ? W2 : V2;
    bf16* dst = (blk < 256) ? W2bf : V2bf;
    int i = ((blk & 255) * 256 + t) * 4;
    float4 v = *(const float4*)(src + i);
    bf16 o[4] = {__float2bfloat16(v.x), __float2bfloat16(v.y),
                 __float2bfloat16(v.z), __float2bfloat16(v.w)};
    *(uint2*)(dst + i) = *(uint2*)o;
  } else {
    int e = (blk - 512) * 1024 + t * 4;
    int d = e >> 9, k0 = e & 511;
    bf16 o[4];
#pragma unroll
    for (int j = 0; j < 4; ++j) o[j] = __float2bfloat16(W1[(size_t)(k0 + j) * 64 + d]);
    *(uint2*)(W1T + e) = *(uint2*)o;
  }
}

__global__ __launch_bounds__(256) void zeroJ(float* __restrict__ Jacc) {
  int i = (blockIdx.x * 256 + threadIdx.x) * 4;
  *(float4*)(Jacc + i) = float4{0.f, 0.f, 0.f, 0.f};
}

// ---------------------------------------------------------------------------
// k1: Xbf = bf16(tanh(mu @ W^T + bias)); D1out = bf16(1 - tanh^2). K=64.
// ---------------------------------------------------------------------------
__global__ __launch_bounds__(256) void k1_stage1(
    const float* __restrict__ states,
    const float* __restrict__ W, const float* __restrict__ bias,
    bf16* __restrict__ out, bf16* __restrict__ d1out) {
  __shared__ __align__(16) float aT[64 * 68];
  __shared__ __align__(16) float wT[64 * 68];
  const int bt = blockIdx.x * 64;
  const int ht = blockIdx.y * 64;
  const int t = threadIdx.x;

#pragma unroll
  for (int i = 0; i < 16; ++i) {
    int idx = t + i * 256;
    int r = idx >> 6, k = idx & 63;
    aT[k * 68 + r] = states[(size_t)(bt + r) * 128 + k];
    wT[k * 68 + r] = W[(size_t)(ht + r) * 64 + k];
  }
  __syncthreads();

  const int bi = (t & 15) * 4, hj = (t >> 4) * 4;
  float acc[4][4] = {};
#pragma unroll
  for (int k = 0; k < 64; ++k) {
    float4 av = *(const float4*)(aT + k * 68 + bi);
    float4 bv = *(const float4*)(wT + k * 68 + hj);
    float ar[4] = {av.x, av.y, av.z, av.w};
    float br[4] = {bv.x, bv.y, bv.z, bv.w};
#pragma unroll
    for (int i = 0; i < 4; ++i)
#pragma unroll
      for (int j = 0; j < 4; ++j) acc[i][j] += ar[i] * br[j];
  }
#pragma unroll
  for (int j = 0; j < 4; ++j) {
    float bsv = bias[ht + hj + j];
#pragma unroll
    for (int i = 0; i < 4; ++i) {
      float x = tanhf(acc[i][j] + bsv);
      size_t o = (size_t)(bt + bi + i) * HH + ht + hj + j;
      out[o] = __float2bfloat16(x);
      d1out[o] = __float2bfloat16(1.0f - x * x);
    }
  }
}

// ---------------------------------------------------------------------------
// k2 (MFMA, LDS-staged): Ybf = bf16(tanh(Xbf @ Wbf^T + bias)). K=512.
// grid (B/64, H/64) = 512 blocks; block 64x64, BK=64, stride-72 LDS.
// ---------------------------------------------------------------------------
__global__ __launch_bounds__(256) void k2_mfma(
    const bf16* __restrict__ A, const bf16* __restrict__ Wbf,
    const float* __restrict__ bias, bf16* __restrict__ out) {
  __shared__ __align__(16) bf16 As[64 * 72];
  __shared__ __align__(16) bf16 Bs[64 * 72];
  const int bt = blockIdx.x * 64;
  const int ht = blockIdx.y * 64;
  const int t = threadIdx.x;
  const int lane = t & 63;
  const int w = t >> 6, wm = w & 1, wn = w >> 1;
  const int c = lane & 15, q = lane >> 4;

  f32x4 acc[2][2] = {};
  for (int kc = 0; kc < 8; ++kc) {
    __syncthreads();
#pragma unroll
    for (int i = 0; i < 2; ++i) {
      int u = t + i * 256;
      int row = u >> 3, kb = (u & 7) * 8;
      *(uint4*)(As + row * 72 + kb) =
          *(const uint4*)(A + (size_t)(bt + row) * HH + kc * 64 + kb);
      *(uint4*)(Bs + row * 72 + kb) =
          *(const uint4*)(Wbf + (size_t)(ht + row) * HH + kc * 64 + kb);
    }
    __syncthreads();
#pragma unroll
    for (int s = 0; s < 2; ++s) {
      bf16x8 af[2], bfr[2];
#pragma unroll
      for (int mt = 0; mt < 2; ++mt)
        af[mt] = __builtin_bit_cast(bf16x8,
            *(const uint4*)(As + (wm * 32 + mt * 16 + c) * 72 + s * 32 + q * 8));
#pragma unroll
      for (int nt = 0; nt < 2; ++nt)
        bfr[nt] = __builtin_bit_cast(bf16x8,
            *(const uint4*)(Bs + (wn * 32 + nt * 16 + c) * 72 + s * 32 + q * 8));
#pragma unroll
      for (int mt = 0; mt < 2; ++mt)
#pragma unroll
        for (int nt = 0; nt < 2; ++nt)
          acc[mt][nt] = __builtin_amdgcn_mfma_f32_16x16x32_bf16(
              af[mt], bfr[nt], acc[mt][nt], 0, 0, 0);
    }
  }
#pragma unroll
  for (int nt = 0; nt < 2; ++nt) {
    int col = ht + wn * 32 + nt * 16 + c;
    float bs = bias[col];
#pragma unroll
    for (int mt = 0; mt < 2; ++mt)
#pragma unroll
      for (int r = 0; r < 4; ++r) {
        int b = bt + wm * 32 + mt * 16 + q * 4 + r;
        out[(size_t)b * HH + col] = __float2bfloat16(tanhf(acc[mt][nt][r] + bs));
      }
  }
}

// ---------------------------------------------------------------------------
// k3: tmp = A @ W^T + bias (A bf16 Bx512, W f32 64x512). act? softplus. f32 out.
// Vectorized bf16 A staging (uint4 load + unpack).
// ---------------------------------------------------------------------------
__global__ __launch_bounds__(256) void k3_stage3(
    const bf16* __restrict__ A,
    const float* __restrict__ W, const float* __restrict__ bias,
    float* __restrict__ out, int colOff, int act) {
  __shared__ __align__(16) float aT[32 * 68];
  __shared__ __align__(16) float wT[32 * 68];
  const int bt = blockIdx.x * 64;
  const int t = threadIdx.x;
  const int bi = (t & 15) * 4, oj = (t >> 4) * 4;
  float acc[4][4] = {};

  for (int kc = 0; kc < HH; kc += 32) {
    {
      int row = t >> 2, kb = (t & 3) * 8;
      uint4 raw = *(const uint4*)(A + (size_t)(bt + row) * HH + kc + kb);
      const unsigned short* xs = (const unsigned short*)&raw;
#pragma unroll
      for (int j = 0; j < 8; ++j) aT[(kb + j) * 68 + row] = u16tof(xs[j]);
    }
#pragma unroll
    for (int i = 0; i < 8; ++i) {
      int idx = t + i * 256;
      int r = idx >> 5, k = idx & 31;
      wT[k * 68 + r] = W[(size_t)r * HH + kc + k];
    }
    __syncthreads();
#pragma unroll
    for (int k = 0; k < 32; ++k) {
      float4 av = *(const float4*)(aT + k * 68 + bi);
      float4 bv = *(const float4*)(wT + k * 68 + oj);
      float ar[4] = {av.x, av.y, av.z, av.w};
      float br[4] = {bv.x, bv.y, bv.z, bv.w};
#pragma unroll
      for (int i = 0; i < 4; ++i)
#pragma unroll
        for (int j = 0; j < 4; ++j) acc[i][j] += ar[i] * br[j];
    }
    __syncthreads();
  }
#pragma unroll
  for (int j = 0; j < 4; ++j) {
    float bsv = bias[oj + j];
#pragma unroll
    for (int i = 0; i < 4; ++i) {
      float v = acc[i][j] + bsv;
      if (act) v = fmaxf(v, 0.0f) + log1pf(expf(-fabsf(v)));
      out[(size_t)(bt + bi + i) * 128 + colOff + oj + j] = v;
    }
  }
}

// ---------------------------------------------------------------------------
// k4 (per-d GEMM, m97-shaped): grid (32, 4, 64) = 8192 blocks, 128x128 tile.
// C_d = D1 @ B_d^T with B_d[h,k] = W2[h,k]*W1[k,d] built in LDS.
// Epilogue: Jacc[b,d] += sum_h C_d[b,h]*(1-h2^2)*W3[d,h]  (atomicAdd).
// LDS ~38 KB -> ~3 blocks/CU.
// ---------------------------------------------------------------------------
__global__ __launch_bounds__(256) void k4_gemm(
    const bf16* __restrict__ D1bf, const bf16* __restrict__ Ybf,
    const bf16* __restrict__ W1T, const bf16* __restrict__ W2bf,
    const float* __restrict__ W3, float* __restrict__ Jacc) {
  __shared__ __align__(16) bf16 As[128 * 72];   // 18432 B
  __shared__ __align__(16) bf16 Bs[128 * 72];   // 18432 B
  __shared__ __align__(16) bf16 w1c[512];       //  1024 B
  const int bt = blockIdx.x * 128;
  const int h0 = blockIdx.y * 128;
  const int d = blockIdx.z;
  const int t = threadIdx.x;
  const int lane = t & 63;
  const int w = t >> 6, wm = w & 1, wn = w >> 1;
  const int c = lane & 15, q = lane >> 4;

  if (t < 64) *(uint4*)(w1c + t * 8) = *(const uint4*)(W1T + (size_t)d * HH + t * 8);

  f32x4 acc[4][4] = {};
  for (int kc = 0; kc < 8; ++kc) {
    __syncthreads();
    // stage A (pure copy) and build B = W2bf * w1c
#pragma unroll
    for (int i = 0; i < 4; ++i) {
      int u = t + i * 256;
      int row = u >> 3, kb = (u & 7) * 8;
      *(uint4*)(As + row * 72 + kb) =
          *(const uint4*)(D1bf + (size_t)(bt + row) * HH + kc * 64 + kb);
      uint4 wr = *(const uint4*)(W2bf + (size_t)(h0 + row) * HH + kc * 64 + kb);
      uint4 w1r = *(const uint4*)(w1c + kc * 64 + kb);
      const unsigned short* wa = (const unsigned short*)&wr;
      const unsigned short* wb = (const unsigned short*)&w1r;
      bf16 o[8];
#pragma unroll
      for (int j = 0; j < 8; ++j)
        o[j] = __float2bfloat16(u16tof(wa[j]) * u16tof(wb[j]));
      *(uint4*)(Bs + row * 72 + kb) = *(const uint4*)o;
    }
    __syncthreads();
#pragma unroll
    for (int s = 0; s < 2; ++s) {
      bf16x8 af[4], bfr[4];
#pragma unroll
      for (int mt = 0; mt < 4; ++mt)
        af[mt] = __builtin_bit_cast(bf16x8,
            *(const uint4*)(As + (wm * 64 + mt * 16 + c) * 72 + s * 32 + q * 8));
#pragma unroll
      for (int nt = 0; nt < 4; ++nt)
        bfr[nt] = __builtin_bit_cast(bf16x8,
            *(const uint4*)(Bs + (wn * 64 + nt * 16 + c) * 72 + s * 32 + q * 8));
#pragma unroll
      for (int mt = 0; mt < 4; ++mt)
#pragma unroll
        for (int nt = 0; nt < 4; ++nt)
          acc[mt][nt] = __builtin_amdgcn_mfma_f32_16x16x32_bf16(
              af[mt], bfr[nt], acc[mt][nt], 0, 0, 0);
    }
  }

  // epilogue: fold E = (1 - h2^2) * W3[d,h]; reduce over cols; atomicAdd.
  float w3v[4];
#pragma unroll
  for (int nt = 0; nt < 4; ++nt)
    w3v[nt] = W3[(size_t)d * HH + h0 + wn * 64 + nt * 16 + c];
#pragma unroll
  for (int mt = 0; mt < 4; ++mt) {
#pragma unroll
    for (int r = 0; r < 4; ++r) {
      int row = bt + wm * 64 + mt * 16 + q * 4 + r;
      float v = 0.f;
#pragma unroll
      for (int nt = 0; nt < 4; ++nt) {
        float y = bf2f(Ybf[(size_t)row * HH + h0 + wn * 64 + nt * 16 + c]);
        v += acc[mt][nt][r] * (1.0f - y * y) * w3v[nt];
      }
      v += __shfl_xor(v, 1);
      v += __shfl_xor(v, 2);
      v += __shfl_xor(v, 4);
      v += __shfl_xor(v, 8);
      if (c == 0) atomicAdd(Jacc + (size_t)row * DD + d, v);
    }
  }
}

// ---------------------------------------------------------------------------
// combine: out[b,64+d] = 2*Jacc[b,d]*sigma[b,d] + out[b,64+d] (Qd stash)
// ---------------------------------------------------------------------------
__global__ __launch_bounds__(256) void combine(
    const float* __restrict__ Jacc, const float* __restrict__ states,
    float* __restrict__ out) {
  int idx = blockIdx.x * 256 + threadIdx.x;
  int b = idx >> 6, d = idx & 63;
  float sig = states[(size_t)b * 128 + 64 + d];
  float qd = out[(size_t)b * 128 + 64 + d];
  out[(size_t)b * 128 + 64 + d] = 2.0f * Jacc[idx] * sig + qd;
}

extern "C" void kernel_launch(void* const* d_in, const int* in_sizes, int n_in,
                              void* d_out, int out_size, void* d_ws, size_t ws_size,
                              hipStream_t stream) {
  // inputs: 0:t 1:states 2:W1 3:b1 4:W2 5:b2 6:W3 7:b3 8:V1 9:c1 10:V2 11:c2 12:V3 13:c3
  const float* states = (const float*)d_in[1];
  const float* W1 = (const float*)d_in[2];
  const float* b1 = (const float*)d_in[3];
  const float* W2 = (const float*)d_in[4];
  const float* b2 = (const float*)d_in[5];
  const float* W3 = (const float*)d_in[6];
  const float* b3 = (const float*)d_in[7];
  const float* V1 = (const float*)d_in[8];
  const float* c1 = (const float*)d_in[9];
  const float* V2 = (const float*)d_in[10];
  const float* c2 = (const float*)d_in[11];
  const float* V3 = (const float*)d_in[12];
  const float* c3 = (const float*)d_in[13];
  float* out = (float*)d_out;

  bf16* Xbf = (bf16*)d_ws;                         // B*H
  bf16* Ybf = Xbf + (size_t)BB * HH;               // B*H
  bf16* D1bf = Ybf + (size_t)BB * HH;              // B*H
  bf16* W2bf = D1bf + (size_t)BB * HH;             // H*H
  bf16* V2bf = W2bf + (size_t)HH * HH;             // H*H
  bf16* W1T = V2bf + (size_t)HH * HH;              // 64*512
  float* Jacc = (float*)(W1T + (size_t)DD * HH);   // B*64 f32

  cvt_weights<<<dim3(544), 256, 0, stream>>>(W2, V2, W1, W2bf, V2bf, W1T);
  zeroJ<<<dim3(256), 256, 0, stream>>>(Jacc);
  // Q path; stash Q_diag (softplus, f32) into out[:, 64:]
  k1_stage1<<<dim3(64, 8), 256, 0, stream>>>(states, V1, c1, Xbf, D1bf);   // g1
  k2_mfma<<<dim3(64, 8), 256, 0, stream>>>(Xbf, V2bf, c2, Ybf);            // g2
  k3_stage3<<<dim3(64), 256, 0, stream>>>(Ybf, V3, c3, out, 64, 1);        // Qd
  // h path
  k1_stage1<<<dim3(64, 8), 256, 0, stream>>>(states, W1, b1, Xbf, D1bf);   // h1, d1
  k2_mfma<<<dim3(64, 8), 256, 0, stream>>>(Xbf, W2bf, b2, Ybf);            // h2
  k3_stage3<<<dim3(64), 256, 0, stream>>>(Ybf, W3, b3, out, 0, 0);         // mu
  // J_diag (64 per-d GEMMs, atomic partials) + final combine
  k4_gemm<<<dim3(32, 4, 64), 256, 0, stream>>>(D1bf, Ybf, W1T, W2bf, W3, Jacc);
  combine<<<dim3(1024), 256, 0, stream>>>(Jacc, states, out);
}

// Round 11
// 627.081 us; speedup vs baseline: 1.1894x; 1.0994x over previous
//
#include <hip/hip_runtime.h>
#include <hip/hip_bf16.h>

#define BB 4096
#define DD 64
#define HH 512

typedef __hip_bfloat16 bf16;
typedef __attribute__((ext_vector_type(8))) short bf16x8;
typedef __attribute__((ext_vector_type(4))) float f32x4;

__device__ __forceinline__ float bf2f(bf16 x) { return __bfloat162float(x); }
__device__ __forceinline__ float u16tof(unsigned short u) {
  union { unsigned int i; float f; } v; v.i = ((unsigned int)u) << 16; return v.f;
}

// ws layout: Xbf (B*H bf16) | Ybf (B*H bf16) | W2bf | V2bf (H*H bf16) |
//            W1T (64x512 bf16) | Jpart (4 x B x 64 f32)   total ~13.1 MB
// Q_diag stashed f32 in out[:,64:] by k3(act=1); combine() adds 2*J*sig.

// ---------------------------------------------------------------------------
// cvt: [0,256) W2bf; [256,512) V2bf; [512,544) W1T[d*512+k] = W1[k*64+d].
// ---------------------------------------------------------------------------
__global__ __launch_bounds__(256) void cvt_weights(
    const float* __restrict__ W2, const float* __restrict__ V2,
    const float* __restrict__ W1,
    bf16* __restrict__ W2bf, bf16* __restrict__ V2bf, bf16* __restrict__ W1T) {
  int blk = blockIdx.x, t = threadIdx.x;
  if (blk < 512) {
    const float* src = (blk < 256) ? W2 : V2;
    bf16* dst = (blk < 256) ? W2bf : V2bf;
    int i = ((blk & 255) * 256 + t) * 4;
    float4 v = *(const float4*)(src + i);
    bf16 o[4] = {__float2bfloat16(v.x), __float2bfloat16(v.y),
                 __float2bfloat16(v.z), __float2bfloat16(v.w)};
    *(uint2*)(dst + i) = *(uint2*)o;
  } else {
    int e = (blk - 512) * 1024 + t * 4;
    int d = e >> 9, k0 = e & 511;
    bf16 o[4];
#pragma unroll
    for (int j = 0; j < 4; ++j) o[j] = __float2bfloat16(W1[(size_t)(k0 + j) * 64 + d]);
    *(uint2*)(W1T + e) = *(uint2*)o;
  }
}

// ---------------------------------------------------------------------------
// k1: Xbf = bf16(tanh(mu @ W^T + bias)), K=64.
// ---------------------------------------------------------------------------
__global__ __launch_bounds__(256) void k1_stage1(
    const float* __restrict__ states,
    const float* __restrict__ W, const float* __restrict__ bias,
    bf16* __restrict__ out) {
  __shared__ __align__(16) float aT[64 * 68];
  __shared__ __align__(16) float wT[64 * 68];
  const int bt = blockIdx.x * 64;
  const int ht = blockIdx.y * 64;
  const int t = threadIdx.x;

#pragma unroll
  for (int i = 0; i < 16; ++i) {
    int idx = t + i * 256;
    int r = idx >> 6, k = idx & 63;
    aT[k * 68 + r] = states[(size_t)(bt + r) * 128 + k];
    wT[k * 68 + r] = W[(size_t)(ht + r) * 64 + k];
  }
  __syncthreads();

  const int bi = (t & 15) * 4, hj = (t >> 4) * 4;
  float acc[4][4] = {};
#pragma unroll
  for (int k = 0; k < 64; ++k) {
    float4 av = *(const float4*)(aT + k * 68 + bi);
    float4 bv = *(const float4*)(wT + k * 68 + hj);
    float ar[4] = {av.x, av.y, av.z, av.w};
    float br[4] = {bv.x, bv.y, bv.z, bv.w};
#pragma unroll
    for (int i = 0; i < 4; ++i)
#pragma unroll
      for (int j = 0; j < 4; ++j) acc[i][j] += ar[i] * br[j];
  }
#pragma unroll
  for (int j = 0; j < 4; ++j) {
    float bsv = bias[ht + hj + j];
#pragma unroll
    for (int i = 0; i < 4; ++i)
      out[(size_t)(bt + bi + i) * HH + ht + hj + j] =
          __float2bfloat16(tanhf(acc[i][j] + bsv));
  }
}

// ---------------------------------------------------------------------------
// k2 (MFMA, LDS-staged): Ybf = bf16(tanh(Xbf @ Wbf^T + bias)). K=512.
// grid (B/64, H/64) = 512 blocks; 64x64 tile, BK=64, stride-72 LDS.
// ---------------------------------------------------------------------------
__global__ __launch_bounds__(256) void k2_mfma(
    const bf16* __restrict__ A, const bf16* __restrict__ Wbf,
    const float* __restrict__ bias, bf16* __restrict__ out) {
  __shared__ __align__(16) bf16 As[64 * 72];
  __shared__ __align__(16) bf16 Bs[64 * 72];
  const int bt = blockIdx.x * 64;
  const int ht = blockIdx.y * 64;
  const int t = threadIdx.x;
  const int lane = t & 63;
  const int w = t >> 6, wm = w & 1, wn = w >> 1;
  const int c = lane & 15, q = lane >> 4;

  f32x4 acc[2][2] = {};
  for (int kc = 0; kc < 8; ++kc) {
    __syncthreads();
#pragma unroll
    for (int i = 0; i < 2; ++i) {
      int u = t + i * 256;
      int row = u >> 3, kb = (u & 7) * 8;
      *(uint4*)(As + row * 72 + kb) =
          *(const uint4*)(A + (size_t)(bt + row) * HH + kc * 64 + kb);
      *(uint4*)(Bs + row * 72 + kb) =
          *(const uint4*)(Wbf + (size_t)(ht + row) * HH + kc * 64 + kb);
    }
    __syncthreads();
#pragma unroll
    for (int s = 0; s < 2; ++s) {
      bf16x8 af[2], bfr[2];
#pragma unroll
      for (int mt = 0; mt < 2; ++mt)
        af[mt] = __builtin_bit_cast(bf16x8,
            *(const uint4*)(As + (wm * 32 + mt * 16 + c) * 72 + s * 32 + q * 8));
#pragma unroll
      for (int nt = 0; nt < 2; ++nt)
        bfr[nt] = __builtin_bit_cast(bf16x8,
            *(const uint4*)(Bs + (wn * 32 + nt * 16 + c) * 72 + s * 32 + q * 8));
#pragma unroll
      for (int mt = 0; mt < 2; ++mt)
#pragma unroll
        for (int nt = 0; nt < 2; ++nt)
          acc[mt][nt] = __builtin_amdgcn_mfma_f32_16x16x32_bf16(
              af[mt], bfr[nt], acc[mt][nt], 0, 0, 0);
    }
  }
#pragma unroll
  for (int nt = 0; nt < 2; ++nt) {
    int col = ht + wn * 32 + nt * 16 + c;
    float bs = bias[col];
#pragma unroll
    for (int mt = 0; mt < 2; ++mt)
#pragma unroll
      for (int r = 0; r < 4; ++r) {
        int b = bt + wm * 32 + mt * 16 + q * 4 + r;
        out[(size_t)b * HH + col] = __float2bfloat16(tanhf(acc[mt][nt][r] + bs));
      }
  }
}

// ---------------------------------------------------------------------------
// k3: tmp = A @ W^T + bias (A bf16 Bx512, W f32 64x512). act? softplus. f32 out.
// ---------------------------------------------------------------------------
__global__ __launch_bounds__(256) void k3_stage3(
    const bf16* __restrict__ A,
    const float* __restrict__ W, const float* __restrict__ bias,
    float* __restrict__ out, int colOff, int act) {
  __shared__ __align__(16) float aT[32 * 68];
  __shared__ __align__(16) float wT[32 * 68];
  const int bt = blockIdx.x * 64;
  const int t = threadIdx.x;
  const int bi = (t & 15) * 4, oj = (t >> 4) * 4;
  float acc[4][4] = {};

  for (int kc = 0; kc < HH; kc += 32) {
    {
      int row = t >> 2, kb = (t & 3) * 8;
      uint4 raw = *(const uint4*)(A + (size_t)(bt + row) * HH + kc + kb);
      const unsigned short* xs = (const unsigned short*)&raw;
#pragma unroll
      for (int j = 0; j < 8; ++j) aT[(kb + j) * 68 + row] = u16tof(xs[j]);
    }
#pragma unroll
    for (int i = 0; i < 8; ++i) {
      int idx = t + i * 256;
      int r = idx >> 5, k = idx & 31;
      wT[k * 68 + r] = W[(size_t)r * HH + kc + k];
    }
    __syncthreads();
#pragma unroll
    for (int k = 0; k < 32; ++k) {
      float4 av = *(const float4*)(aT + k * 68 + bi);
      float4 bv = *(const float4*)(wT + k * 68 + oj);
      float ar[4] = {av.x, av.y, av.z, av.w};
      float br[4] = {bv.x, bv.y, bv.z, bv.w};
#pragma unroll
      for (int i = 0; i < 4; ++i)
#pragma unroll
        for (int j = 0; j < 4; ++j) acc[i][j] += ar[i] * br[j];
    }
    __syncthreads();
  }
#pragma unroll
  for (int j = 0; j < 4; ++j) {
    float bsv = bias[oj + j];
#pragma unroll
    for (int i = 0; i < 4; ++i) {
      float v = acc[i][j] + bsv;
      if (act) v = fmaxf(v, 0.0f) + log1pf(expf(-fabsf(v)));
      out[(size_t)(bt + bi + i) * 128 + colOff + oj + j] = v;
    }
  }
}

// ---------------------------------------------------------------------------
// k4 v5: grid (32 bt, 4 h0, 64 d), 128x128 tile, BK=64, no atomics.
// A[b,k] = (1-Xbf^2) built on the fly; B[h,k] = W2bf*W1T[d,k]*W3[d,h].
// Epilogue: d2 tile staged to LDS (reusing As/Bs), fold, shfl-reduce over h,
// write Jpart[h0-plane][b][d].  LDS 38.4 KB -> 4 blocks/CU.
// ---------------------------------------------------------------------------
__global__ __launch_bounds__(256) void k4_gemm(
    const bf16* __restrict__ Xbf, const bf16* __restrict__ Ybf,
    const bf16* __restrict__ W1T, const bf16* __restrict__ W2bf,
    const float* __restrict__ W3, float* __restrict__ Jpart) {
  __shared__ __align__(16) bf16 smem[128 * 72 * 2];  // As | Bs ; reused as Ds
  __shared__ __align__(16) bf16 w1c[512];
  __shared__ __align__(16) float w3s[128];
  bf16* As = smem;
  bf16* Bs = smem + 128 * 72;
  const int bt = blockIdx.x * 128;
  const int h0 = blockIdx.y * 128;
  const int d = blockIdx.z;
  const int t = threadIdx.x;
  const int lane = t & 63;
  const int w = t >> 6, wm = w & 1, wn = w >> 1;
  const int c = lane & 15, q = lane >> 4;

  if (t < 64) *(uint4*)(w1c + t * 8) = *(const uint4*)(W1T + (size_t)d * HH + t * 8);
  if (t >= 64 && t < 192) w3s[t - 64] = W3[(size_t)d * HH + h0 + (t - 64)];

  f32x4 acc[4][4] = {};
  for (int kc = 0; kc < 8; ++kc) {
    __syncthreads();   // w1c/w3s visible (1st iter); prev frag reads done
#pragma unroll
    for (int i = 0; i < 4; ++i) {
      int u = t + i * 256;
      int row = u >> 3, kb = (u & 7) * 8;
      // A = d1 from Xbf
      uint4 xr = *(const uint4*)(Xbf + (size_t)(bt + row) * HH + kc * 64 + kb);
      const unsigned short* xs = (const unsigned short*)&xr;
      bf16 oa[8];
#pragma unroll
      for (int j = 0; j < 8; ++j) {
        float x = u16tof(xs[j]);
        oa[j] = __float2bfloat16(1.0f - x * x);
      }
      *(uint4*)(As + row * 72 + kb) = *(const uint4*)oa;
      // B = W2 * w1c * w3s[row]
      uint4 wr = *(const uint4*)(W2bf + (size_t)(h0 + row) * HH + kc * 64 + kb);
      uint4 w1r = *(const uint4*)(w1c + kc * 64 + kb);
      const unsigned short* wa = (const unsigned short*)&wr;
      const unsigned short* wb = (const unsigned short*)&w1r;
      float w3v = w3s[row];
      bf16 ob[8];
#pragma unroll
      for (int j = 0; j < 8; ++j)
        ob[j] = __float2bfloat16(u16tof(wa[j]) * u16tof(wb[j]) * w3v);
      *(uint4*)(Bs + row * 72 + kb) = *(const uint4*)ob;
    }
    __syncthreads();
#pragma unroll
    for (int s = 0; s < 2; ++s) {
      bf16x8 af[4], bfr[4];
#pragma unroll
      for (int mt = 0; mt < 4; ++mt)
        af[mt] = __builtin_bit_cast(bf16x8,
            *(const uint4*)(As + (wm * 64 + mt * 16 + c) * 72 + s * 32 + q * 8));
#pragma unroll
      for (int nt = 0; nt < 4; ++nt)
        bfr[nt] = __builtin_bit_cast(bf16x8,
            *(const uint4*)(Bs + (wn * 64 + nt * 16 + c) * 72 + s * 32 + q * 8));
#pragma unroll
      for (int mt = 0; mt < 4; ++mt)
#pragma unroll
        for (int nt = 0; nt < 4; ++nt)
          acc[mt][nt] = __builtin_amdgcn_mfma_f32_16x16x32_bf16(
              af[mt], bfr[nt], acc[mt][nt], 0, 0, 0);
    }
  }

  // ---- epilogue: stage d2 tile (reuse smem), fold, reduce over h, write ----
  __syncthreads();
  bf16* Ds = smem;  // 128 x 136 (17408 elems <= 18432 available)
#pragma unroll
  for (int i = 0; i < 8; ++i) {
    int u = t + i * 256;
    int row = u >> 4, cg = (u & 15) * 8;
    uint4 yr = *(const uint4*)(Ybf + (size_t)(bt + row) * HH + h0 + cg);
    const unsigned short* ys = (const unsigned short*)&yr;
    bf16 o[8];
#pragma unroll
    for (int j = 0; j < 8; ++j) {
      float y = u16tof(ys[j]);
      o[j] = __float2bfloat16(1.0f - y * y);
    }
    *(uint4*)(Ds + row * 136 + cg) = *(const uint4*)o;
  }
  __syncthreads();
#pragma unroll
  for (int mt = 0; mt < 4; ++mt) {
#pragma unroll
    for (int r = 0; r < 4; ++r) {
      int m = wm * 64 + mt * 16 + q * 4 + r;
      float v = 0.f;
#pragma unroll
      for (int nt = 0; nt < 4; ++nt) {
        int n = wn * 64 + nt * 16 + c;
        v += acc[mt][nt][r] * bf2f(Ds[m * 136 + n]);
      }
      v += __shfl_xor(v, 1);
      v += __shfl_xor(v, 2);
      v += __shfl_xor(v, 4);
      v += __shfl_xor(v, 8);
      if (c == 0)
        Jpart[((size_t)blockIdx.y * BB + bt + m) * 64 + d] = v;
    }
  }
}

// ---------------------------------------------------------------------------
// combine: out[b,64+d] = 2*(sum of 4 Jpart planes)*sigma + out (Qd stash)
// ---------------------------------------------------------------------------
__global__ __launch_bounds__(256) void combine(
    const float* __restrict__ Jpart, const float* __restrict__ states,
    float* __restrict__ out) {
  int idx = blockIdx.x * 256 + threadIdx.x;
  int b = idx >> 6, d = idx & 63;
  const int plane = BB * 64;
  float J = Jpart[idx] + Jpart[plane + idx] + Jpart[2 * plane + idx] +
            Jpart[3 * plane + idx];
  float sig = states[(size_t)b * 128 + 64 + d];
  float qd = out[(size_t)b * 128 + 64 + d];
  out[(size_t)b * 128 + 64 + d] = 2.0f * J * sig + qd;
}

extern "C" void kernel_launch(void* const* d_in, const int* in_sizes, int n_in,
                              void* d_out, int out_size, void* d_ws, size_t ws_size,
                              hipStream_t stream) {
  // inputs: 0:t 1:states 2:W1 3:b1 4:W2 5:b2 6:W3 7:b3 8:V1 9:c1 10:V2 11:c2 12:V3 13:c3
  const float* states = (const float*)d_in[1];
  const float* W1 = (const float*)d_in[2];
  const float* b1 = (const float*)d_in[3];
  const float* W2 = (const float*)d_in[4];
  const float* b2 = (const float*)d_in[5];
  const float* W3 = (const float*)d_in[6];
  const float* b3 = (const float*)d_in[7];
  const float* V1 = (const float*)d_in[8];
  const float* c1 = (const float*)d_in[9];
  const float* V2 = (const float*)d_in[10];
  const float* c2 = (const float*)d_in[11];
  const float* V3 = (const float*)d_in[12];
  const float* c3 = (const float*)d_in[13];
  float* out = (float*)d_out;

  bf16* Xbf = (bf16*)d_ws;                         // B*H  (4 MB)
  bf16* Ybf = Xbf + (size_t)BB * HH;               // B*H  (4 MB)
  bf16* W2bf = Ybf + (size_t)BB * HH;              // H*H  (0.5 MB)
  bf16* V2bf = W2bf + (size_t)HH * HH;             // H*H  (0.5 MB)
  bf16* W1T = V2bf + (size_t)HH * HH;              // 64x512 (64 KB)
  float* Jpart = (float*)(W1T + (size_t)DD * HH);  // 4*B*64 f32 (4 MB)

  cvt_weights<<<dim3(544), 256, 0, stream>>>(W2, V2, W1, W2bf, V2bf, W1T);
  // Q path; stash Q_diag (softplus, f32) into out[:, 64:]
  k1_stage1<<<dim3(64, 8), 256, 0, stream>>>(states, V1, c1, Xbf);       // g1
  k2_mfma<<<dim3(64, 8), 256, 0, stream>>>(Xbf, V2bf, c2, Ybf);          // g2
  k3_stage3<<<dim3(64), 256, 0, stream>>>(Ybf, V3, c3, out, 64, 1);      // Qd
  // h path
  k1_stage1<<<dim3(64, 8), 256, 0, stream>>>(states, W1, b1, Xbf);       // h1
  k2_mfma<<<dim3(64, 8), 256, 0, stream>>>(Xbf, W2bf, b2, Ybf);          // h2
  k3_stage3<<<dim3(64), 256, 0, stream>>>(Ybf, W3, b3, out, 0, 0);       // mu
  // J_diag (per-d GEMMs, private partials) + final combine
  k4_gemm<<<dim3(32, 4, 64), 256, 0, stream>>>(Xbf, Ybf, W1T, W2bf, W3, Jpart);
  combine<<<dim3(1024), 256, 0, stream>>>(Jpart, states, out);
}

// Round 12
// 589.030 us; speedup vs baseline: 1.2662x; 1.0646x over previous
//
#include <hip/hip_runtime.h>
#include <hip/hip_bf16.h>

#define BB 4096
#define DD 64
#define HH 512

typedef __hip_bfloat16 bf16;
typedef __attribute__((ext_vector_type(8))) short bf16x8;
typedef __attribute__((ext_vector_type(4))) float f32x4;

__device__ __forceinline__ float bf2f(bf16 x) { return __bfloat162float(x); }
__device__ __forceinline__ float u16tof(unsigned short u) {
  union { unsigned int i; float f; } v; v.i = ((unsigned int)u) << 16; return v.f;
}

// ws layout: Xbf (B*H bf16) | Ybf (B*H bf16) | W2bf | V2bf (H*H bf16) |
//            W1T (64x512 bf16) | Jpart (4 x B x 64 f32)   total ~13.1 MB
// Q_diag stashed f32 in out[:,64:] by k3(act=1); combine() adds 2*J*sig.

// ---------------------------------------------------------------------------
// cvt: [0,256) W2bf; [256,512) V2bf; [512,544) W1T[d*512+k] = W1[k*64+d].
// ---------------------------------------------------------------------------
__global__ __launch_bounds__(256) void cvt_weights(
    const float* __restrict__ W2, const float* __restrict__ V2,
    const float* __restrict__ W1,
    bf16* __restrict__ W2bf, bf16* __restrict__ V2bf, bf16* __restrict__ W1T) {
  int blk = blockIdx.x, t = threadIdx.x;
  if (blk < 512) {
    const float* src = (blk < 256) ? W2 : V2;
    bf16* dst = (blk < 256) ? W2bf : V2bf;
    int i = ((blk & 255) * 256 + t) * 4;
    float4 v = *(const float4*)(src + i);
    bf16 o[4] = {__float2bfloat16(v.x), __float2bfloat16(v.y),
                 __float2bfloat16(v.z), __float2bfloat16(v.w)};
    *(uint2*)(dst + i) = *(uint2*)o;
  } else {
    int e = (blk - 512) * 1024 + t * 4;
    int d = e >> 9, k0 = e & 511;
    bf16 o[4];
#pragma unroll
    for (int j = 0; j < 4; ++j) o[j] = __float2bfloat16(W1[(size_t)(k0 + j) * 64 + d]);
    *(uint2*)(W1T + e) = *(uint2*)o;
  }
}

// ---------------------------------------------------------------------------
// k1: Xbf = bf16(tanh(mu @ W^T + bias)), K=64.
// ---------------------------------------------------------------------------
__global__ __launch_bounds__(256) void k1_stage1(
    const float* __restrict__ states,
    const float* __restrict__ W, const float* __restrict__ bias,
    bf16* __restrict__ out) {
  __shared__ __align__(16) float aT[64 * 68];
  __shared__ __align__(16) float wT[64 * 68];
  const int bt = blockIdx.x * 64;
  const int ht = blockIdx.y * 64;
  const int t = threadIdx.x;

#pragma unroll
  for (int i = 0; i < 16; ++i) {
    int idx = t + i * 256;
    int r = idx >> 6, k = idx & 63;
    aT[k * 68 + r] = states[(size_t)(bt + r) * 128 + k];
    wT[k * 68 + r] = W[(size_t)(ht + r) * 64 + k];
  }
  __syncthreads();

  const int bi = (t & 15) * 4, hj = (t >> 4) * 4;
  float acc[4][4] = {};
#pragma unroll
  for (int k = 0; k < 64; ++k) {
    float4 av = *(const float4*)(aT + k * 68 + bi);
    float4 bv = *(const float4*)(wT + k * 68 + hj);
    float ar[4] = {av.x, av.y, av.z, av.w};
    float br[4] = {bv.x, bv.y, bv.z, bv.w};
#pragma unroll
    for (int i = 0; i < 4; ++i)
#pragma unroll
      for (int j = 0; j < 4; ++j) acc[i][j] += ar[i] * br[j];
  }
#pragma unroll
  for (int j = 0; j < 4; ++j) {
    float bsv = bias[ht + hj + j];
#pragma unroll
    for (int i = 0; i < 4; ++i)
      out[(size_t)(bt + bi + i) * HH + ht + hj + j] =
          __float2bfloat16(tanhf(acc[i][j] + bsv));
  }
}

// ---------------------------------------------------------------------------
// k2 (MFMA, LDS-staged): Ybf = bf16(tanh(Xbf @ Wbf^T + bias)). K=512.
// grid (B/64, H/64) = 512 blocks; 64x64 tile, BK=64, stride-72 LDS.
// ---------------------------------------------------------------------------
__global__ __launch_bounds__(256) void k2_mfma(
    const bf16* __restrict__ A, const bf16* __restrict__ Wbf,
    const float* __restrict__ bias, bf16* __restrict__ out) {
  __shared__ __align__(16) bf16 As[64 * 72];
  __shared__ __align__(16) bf16 Bs[64 * 72];
  const int bt = blockIdx.x * 64;
  const int ht = blockIdx.y * 64;
  const int t = threadIdx.x;
  const int lane = t & 63;
  const int w = t >> 6, wm = w & 1, wn = w >> 1;
  const int c = lane & 15, q = lane >> 4;

  f32x4 acc[2][2] = {};
  for (int kc = 0; kc < 8; ++kc) {
    __syncthreads();
#pragma unroll
    for (int i = 0; i < 2; ++i) {
      int u = t + i * 256;
      int row = u >> 3, kb = (u & 7) * 8;
      *(uint4*)(As + row * 72 + kb) =
          *(const uint4*)(A + (size_t)(bt + row) * HH + kc * 64 + kb);
      *(uint4*)(Bs + row * 72 + kb) =
          *(const uint4*)(Wbf + (size_t)(ht + row) * HH + kc * 64 + kb);
    }
    __syncthreads();
#pragma unroll
    for (int s = 0; s < 2; ++s) {
      bf16x8 af[2], bfr[2];
#pragma unroll
      for (int mt = 0; mt < 2; ++mt)
        af[mt] = __builtin_bit_cast(bf16x8,
            *(const uint4*)(As + (wm * 32 + mt * 16 + c) * 72 + s * 32 + q * 8));
#pragma unroll
      for (int nt = 0; nt < 2; ++nt)
        bfr[nt] = __builtin_bit_cast(bf16x8,
            *(const uint4*)(Bs + (wn * 32 + nt * 16 + c) * 72 + s * 32 + q * 8));
#pragma unroll
      for (int mt = 0; mt < 2; ++mt)
#pragma unroll
        for (int nt = 0; nt < 2; ++nt)
          acc[mt][nt] = __builtin_amdgcn_mfma_f32_16x16x32_bf16(
              af[mt], bfr[nt], acc[mt][nt], 0, 0, 0);
    }
  }
#pragma unroll
  for (int nt = 0; nt < 2; ++nt) {
    int col = ht + wn * 32 + nt * 16 + c;
    float bs = bias[col];
#pragma unroll
    for (int mt = 0; mt < 2; ++mt)
#pragma unroll
      for (int r = 0; r < 4; ++r) {
        int b = bt + wm * 32 + mt * 16 + q * 4 + r;
        out[(size_t)b * HH + col] = __float2bfloat16(tanhf(acc[mt][nt][r] + bs));
      }
  }
}

// ---------------------------------------------------------------------------
// k3: tmp = A @ W^T + bias (A bf16 Bx512, W f32 64x512). act? softplus. f32 out.
// ---------------------------------------------------------------------------
__global__ __launch_bounds__(256) void k3_stage3(
    const bf16* __restrict__ A,
    const float* __restrict__ W, const float* __restrict__ bias,
    float* __restrict__ out, int colOff, int act) {
  __shared__ __align__(16) float aT[32 * 68];
  __shared__ __align__(16) float wT[32 * 68];
  const int bt = blockIdx.x * 64;
  const int t = threadIdx.x;
  const int bi = (t & 15) * 4, oj = (t >> 4) * 4;
  float acc[4][4] = {};

  for (int kc = 0; kc < HH; kc += 32) {
    {
      int row = t >> 2, kb = (t & 3) * 8;
      uint4 raw = *(const uint4*)(A + (size_t)(bt + row) * HH + kc + kb);
      const unsigned short* xs = (const unsigned short*)&raw;
#pragma unroll
      for (int j = 0; j < 8; ++j) aT[(kb + j) * 68 + row] = u16tof(xs[j]);
    }
#pragma unroll
    for (int i = 0; i < 8; ++i) {
      int idx = t + i * 256;
      int r = idx >> 5, k = idx & 31;
      wT[k * 68 + r] = W[(size_t)r * HH + kc + k];
    }
    __syncthreads();
#pragma unroll
    for (int k = 0; k < 32; ++k) {
      float4 av = *(const float4*)(aT + k * 68 + bi);
      float4 bv = *(const float4*)(wT + k * 68 + oj);
      float ar[4] = {av.x, av.y, av.z, av.w};
      float br[4] = {bv.x, bv.y, bv.z, bv.w};
#pragma unroll
      for (int i = 0; i < 4; ++i)
#pragma unroll
        for (int j = 0; j < 4; ++j) acc[i][j] += ar[i] * br[j];
    }
    __syncthreads();
  }
#pragma unroll
  for (int j = 0; j < 4; ++j) {
    float bsv = bias[oj + j];
#pragma unroll
    for (int i = 0; i < 4; ++i) {
      float v = acc[i][j] + bsv;
      if (act) v = fmaxf(v, 0.0f) + log1pf(expf(-fabsf(v)));
      out[(size_t)(bt + bi + i) * 128 + colOff + oj + j] = v;
    }
  }
}

// ---------------------------------------------------------------------------
// k4 v6 "(b,d)-flattened GEMM": grid (B/2 = 2048, 4 h-tiles), 128x128 tile.
// M-row m = bb*64 + dl (2 b x 64 d per block). A[m,k] = d1[bb,k]*W1T[dl,k]
// (1 bf16 mul/elem); B = W2bf rows (PURE COPY). Epilogue folds
// d2f(f32)*w3s(bf16), shfl-reduce over cols, write Jpart[h-plane][bt*128+m].
// LDS ~59 KB -> 2 blocks/CU. 2 barriers/kc.
// ---------------------------------------------------------------------------
__global__ __launch_bounds__(256) void k4_gemm(
    const bf16* __restrict__ Xbf, const bf16* __restrict__ Ybf,
    const bf16* __restrict__ W1T, const bf16* __restrict__ W2bf,
    const float* __restrict__ W3, float* __restrict__ Jpart) {
  __shared__ __align__(16) bf16 As[128 * 72];      // 18432 B
  __shared__ __align__(16) bf16 Bs[128 * 72];      // 18432 B
  __shared__ __align__(16) bf16 w3s[64 * 136];     // 17408 B
  __shared__ __align__(16) float d1f[2 * 512];     //  4096 B
  __shared__ __align__(16) float d2f[2 * 128];     //  1024 B
  __shared__ float red[256];                       //  1024 B
  const int bt = blockIdx.x;                       // b-pair index
  const int h0 = blockIdx.y * 128;
  const int t = threadIdx.x;
  const int lane = t & 63;
  const int w = t >> 6, wm = w & 1, wn = w >> 1;
  const int c = lane & 15, q = lane >> 4;

  // stage d1f = 1 - h1^2 (2 rows x 512, f32)
#pragma unroll
  for (int i = 0; i < 4; ++i) {
    int e = t + i * 256;
    float x = bf2f(Xbf[(size_t)(bt * 2 + (e >> 9)) * HH + (e & 511)]);
    d1f[e] = 1.0f - x * x;
  }
  // stage d2f = 1 - h2^2 for this h-tile (2 x 128, f32)
  {
    float y = bf2f(Ybf[(size_t)(bt * 2 + (t >> 7)) * HH + h0 + (t & 127)]);
    d2f[t] = 1.0f - y * y;
  }
  // stage w3s = bf16(W3[dl, h0+hl]) (64 x 128, stride 136)
#pragma unroll
  for (int i = 0; i < 8; ++i) {
    int e = (t + i * 256) * 4;
    int dl = e >> 7, hl = e & 127;
    float4 v = *(const float4*)(W3 + (size_t)dl * HH + h0 + hl);
    bf16 o[4] = {__float2bfloat16(v.x), __float2bfloat16(v.y),
                 __float2bfloat16(v.z), __float2bfloat16(v.w)};
    *(uint2*)(w3s + dl * 136 + hl) = *(uint2*)o;
  }
  __syncthreads();

  f32x4 acc[4][4] = {};
  for (int kc = 0; kc < 8; ++kc) {
    // build As (1 mul/elem) + copy Bs
#pragma unroll
    for (int i = 0; i < 4; ++i) {
      int g = t + i * 256;
      int m = g >> 3, kb = (g & 7) * 8;
      int bb = m >> 6, dl = m & 63;
      uint4 w1r = *(const uint4*)(W1T + (size_t)dl * HH + kc * 64 + kb);
      const unsigned short* ws_ = (const unsigned short*)&w1r;
      const float* dp = d1f + bb * 512 + kc * 64 + kb;
      bf16 oa[8];
#pragma unroll
      for (int j = 0; j < 8; ++j)
        oa[j] = __float2bfloat16(dp[j] * u16tof(ws_[j]));
      *(uint4*)(As + m * 72 + kb) = *(const uint4*)oa;
      *(uint4*)(Bs + m * 72 + kb) =
          *(const uint4*)(W2bf + (size_t)(h0 + m) * HH + kc * 64 + kb);
    }
    __syncthreads();
#pragma unroll
    for (int s = 0; s < 2; ++s) {
      bf16x8 af[4], bfr[4];
#pragma unroll
      for (int mt = 0; mt < 4; ++mt)
        af[mt] = __builtin_bit_cast(bf16x8,
            *(const uint4*)(As + (wm * 64 + mt * 16 + c) * 72 + s * 32 + q * 8));
#pragma unroll
      for (int nt = 0; nt < 4; ++nt)
        bfr[nt] = __builtin_bit_cast(bf16x8,
            *(const uint4*)(Bs + (wn * 64 + nt * 16 + c) * 72 + s * 32 + q * 8));
#pragma unroll
      for (int mt = 0; mt < 4; ++mt)
#pragma unroll
        for (int nt = 0; nt < 4; ++nt)
          acc[mt][nt] = __builtin_amdgcn_mfma_f32_16x16x32_bf16(
              af[mt], bfr[nt], acc[mt][nt], 0, 0, 0);
    }
    __syncthreads();
  }

  // epilogue: v[m] = sum_n C[m,n] * d2f[bb,n] * w3s[dl,n]; reduce over c lanes
#pragma unroll
  for (int mt = 0; mt < 4; ++mt) {
#pragma unroll
    for (int r = 0; r < 4; ++r) {
      int m = wm * 64 + mt * 16 + q * 4 + r;
      int bb = m >> 6, dl = m & 63;
      float v = 0.f;
#pragma unroll
      for (int nt = 0; nt < 4; ++nt) {
        int n = wn * 64 + nt * 16 + c;
        v += acc[mt][nt][r] * d2f[bb * 128 + n] * bf2f(w3s[dl * 136 + n]);
      }
      v += __shfl_xor(v, 1);
      v += __shfl_xor(v, 2);
      v += __shfl_xor(v, 4);
      v += __shfl_xor(v, 8);
      if (c == 0) red[wn * 128 + m] = v;
    }
  }
  __syncthreads();
  if (t < 128) {
    float J = red[t] + red[128 + t];
    Jpart[(size_t)blockIdx.y * (BB * 64) + (size_t)bt * 128 + t] = J;
  }
}

// ---------------------------------------------------------------------------
// combine: out[b,64+d] = 2*(sum of 4 Jpart planes)*sigma + out (Qd stash)
// ---------------------------------------------------------------------------
__global__ __launch_bounds__(256) void combine(
    const float* __restrict__ Jpart, const float* __restrict__ states,
    float* __restrict__ out) {
  int idx = blockIdx.x * 256 + threadIdx.x;
  int b = idx >> 6, d = idx & 63;
  const int plane = BB * 64;
  float J = Jpart[idx] + Jpart[plane + idx] + Jpart[2 * plane + idx] +
            Jpart[3 * plane + idx];
  float sig = states[(size_t)b * 128 + 64 + d];
  float qd = out[(size_t)b * 128 + 64 + d];
  out[(size_t)b * 128 + 64 + d] = 2.0f * J * sig + qd;
}

extern "C" void kernel_launch(void* const* d_in, const int* in_sizes, int n_in,
                              void* d_out, int out_size, void* d_ws, size_t ws_size,
                              hipStream_t stream) {
  // inputs: 0:t 1:states 2:W1 3:b1 4:W2 5:b2 6:W3 7:b3 8:V1 9:c1 10:V2 11:c2 12:V3 13:c3
  const float* states = (const float*)d_in[1];
  const float* W1 = (const float*)d_in[2];
  const float* b1 = (const float*)d_in[3];
  const float* W2 = (const float*)d_in[4];
  const float* b2 = (const float*)d_in[5];
  const float* W3 = (const float*)d_in[6];
  const float* b3 = (const float*)d_in[7];
  const float* V1 = (const float*)d_in[8];
  const float* c1 = (const float*)d_in[9];
  const float* V2 = (const float*)d_in[10];
  const float* c2 = (const float*)d_in[11];
  const float* V3 = (const float*)d_in[12];
  const float* c3 = (const float*)d_in[13];
  float* out = (float*)d_out;

  bf16* Xbf = (bf16*)d_ws;                         // B*H  (4 MB)
  bf16* Ybf = Xbf + (size_t)BB * HH;               // B*H  (4 MB)
  bf16* W2bf = Ybf + (size_t)BB * HH;              // H*H  (0.5 MB)
  bf16* V2bf = W2bf + (size_t)HH * HH;             // H*H  (0.5 MB)
  bf16* W1T = V2bf + (size_t)HH * HH;              // 64x512 (64 KB)
  float* Jpart = (float*)(W1T + (size_t)DD * HH);  // 4*B*64 f32 (4 MB)

  cvt_weights<<<dim3(544), 256, 0, stream>>>(W2, V2, W1, W2bf, V2bf, W1T);
  // Q path; stash Q_diag (softplus, f32) into out[:, 64:]
  k1_stage1<<<dim3(64, 8), 256, 0, stream>>>(states, V1, c1, Xbf);       // g1
  k2_mfma<<<dim3(64, 8), 256, 0, stream>>>(Xbf, V2bf, c2, Ybf);          // g2
  k3_stage3<<<dim3(64), 256, 0, stream>>>(Ybf, V3, c3, out, 64, 1);      // Qd
  // h path
  k1_stage1<<<dim3(64, 8), 256, 0, stream>>>(states, W1, b1, Xbf);       // h1
  k2_mfma<<<dim3(64, 8), 256, 0, stream>>>(Xbf, W2bf, b2, Ybf);          // h2
  k3_stage3<<<dim3(64), 256, 0, stream>>>(Ybf, W3, b3, out, 0, 0);       // mu
  // J_diag ((b,d)-flattened GEMM, private partials) + final combine
  k4_gemm<<<dim3(2048, 4), 256, 0, stream>>>(Xbf, Ybf, W1T, W2bf, W3, Jpart);
  combine<<<dim3(1024), 256, 0, stream>>>(Jpart, states, out);
}